// Round 15
// baseline (47.403 us; speedup 1.0000x reference)
//
#include <hip/hip_runtime.h>

#define B 32
#define L 200
#define DIN 64
#define H 64
#define A 36

typedef __attribute__((ext_vector_type(8))) short short8;   // bf16 MFMA fragment
typedef __attribute__((ext_vector_type(4))) float floatx4;  // MFMA accumulator
typedef __attribute__((ext_vector_type(8))) float floatx8;

static __device__ __forceinline__ short f2bf(float f) {
    union { float f; unsigned u; } v; v.f = f;
    unsigned r = (v.u + 0x7FFF + ((v.u >> 16) & 1)) >> 16;  // RNE
    return (short)r;
}

// Kernel 1: h = x@ln_w + ln_b ; h f32, hb16 pre-swizzled bf16. NO cc here
// (moved to score prologue). Block 0 reorders w1a/w1b/w1c into fragment order.
__global__ __launch_bounds__(256) void prep_kernel(
    const float* __restrict__ x, const float* __restrict__ ln_w,
    const float* __restrict__ ln_b, const float* __restrict__ w1,
    float* __restrict__ h_out, short* __restrict__ hb16_out,
    float* __restrict__ w1a_r, float* __restrict__ w1b_r, float* __restrict__ w1c_r)
{
    int wave = threadIdx.x >> 6;
    int lane = threadIdx.x & 63;
    int bl = __builtin_amdgcn_readfirstlane(blockIdx.x * 4 + wave);
    const float* xr = x + (size_t)bl * DIN;
    float p0 = ln_b[lane], p1 = 0.f;
    #pragma unroll
    for (int d = 0; d < DIN; d += 2) {
        p0 = fmaf(xr[d],     ln_w[d * H + lane],       p0);   // xr uniform -> s_load
        p1 = fmaf(xr[d + 1], ln_w[(d + 1) * H + lane], p1);
    }
    float acc = p0 + p1;
    h_out[(size_t)bl * H + lane] = acc;
    int j = bl % L;
    hb16_out[(size_t)bl * H + (lane ^ ((j & 7) << 3))] = f2bf(acc);   // swizzled
    if (blockIdx.x == 0) {
        // fragment-order tables: idx = ((s*3+n)*64 + lane)*8 + e
        for (int idx = threadIdx.x; idx < 2 * 3 * 64 * 8; idx += 256) {
            int e = idx & 7, ln = (idx >> 3) & 63, sn = idx >> 9;
            int s = sn / 3, n = sn - 3 * s;
            int k = s * 32 + (ln >> 4) * 8 + e;
            int c = n * 16 + (ln & 15);
            bool cv = c < A;
            w1a_r[idx] = cv ? w1[k * A + c] : 0.f;
            w1b_r[idx] = cv ? w1[(H + k) * A + c] : 0.f;
            w1c_r[idx] = cv ? w1[(2 * H + k) * A + c] : 0.f;
        }
    }
}

// Kernel 2: block=(b,g), g reversed (longest first); wave w owns i = 4g+w.
// mmax is BLOCK-uniform (4g mod 16 in {0,4,8,12}). Stage rows 0..(4g+3|15).
// cc computed in prologue (w1b_r table + xor-reduce). m-loop is 2-WIDE:
// two independent m-tiles per iteration (2x frags/accums/epilogue/PV) to
// halve the per-wave serial latency chain.
__global__ void score_kernel(
    const float* __restrict__ h, const short* __restrict__ hb16,
    const float* __restrict__ w1a_r, const float* __restrict__ w1b_r,
    const float* __restrict__ w1c_r, const float* __restrict__ b1,
    const float* __restrict__ w2, const float* __restrict__ b2,
    float* __restrict__ out)
{
    int blk = blockIdx.x;
    int b  = blk / 50;
    int g  = 49 - (blk - b * 50);            // longest blocks dispatch first
    int wave = threadIdx.x >> 6;
    int lane = threadIdx.x & 63;
    int i = __builtin_amdgcn_readfirstlane(4 * g + wave);     // 0..199
    int l15 = lane & 15, l4 = lane >> 4;

    __shared__ __align__(16) short tile[208 * 64];  // pre-swizzled rows

    const short* hb16b = hb16 + (size_t)b * L * H;
    const float* h_b   = h + (size_t)b * L * H;

    // ---- stage rows 0 .. (4g+3 | 15): 2..26 chunks of 8 rows ----
    int maxrow = 4 * g + 3;
    int nch = (((maxrow | 15) + 1) + 7) >> 3;
    for (int c = wave; c < nch; c += 4) {
        int j = c * 8 + (lane >> 3); if (j > L - 1) j = L - 1;
        const short* src = hb16b + (size_t)j * H + (lane & 7) * 8;
        __builtin_amdgcn_global_load_lds(
            (const __attribute__((address_space(1))) void*)src,
            (__attribute__((address_space(3))) void*)&tile[c * 512],
            16, 0, 0);
    }

    // ---- prologue (overlaps staging flight) ----
    const float* hi = h_b + (size_t)i * H;            // uniform -> s_load
    float b2v = b2[0];
    float hik[2][8];
    #pragma unroll
    for (int s = 0; s < 2; ++s) {
        floatx8 hv = *(const floatx8*)(hi + s * 32 + l4 * 8);
        #pragma unroll
        for (int e = 0; e < 8; ++e) hik[s][e] = hv[e];
    }
    // cc[i,c] for c = n*16+l15 : 48 fma vs w1b_r, then reduce over l4 groups
    float ccn[3];
    short8 afrag[2][3];
    #pragma unroll
    for (int n = 0; n < 3; ++n) ccn[n] = 0.f;
    #pragma unroll
    for (int s = 0; s < 2; ++s) {
        #pragma unroll
        for (int n = 0; n < 3; ++n) {
            int base = (((s * 3 + n) * 64) + lane) * 8;
            floatx8 wa = *(const floatx8*)&w1a_r[base];
            floatx8 wb = *(const floatx8*)&w1b_r[base];
            floatx8 wc = *(const floatx8*)&w1c_r[base];
            #pragma unroll
            for (int e = 0; e < 8; ++e) {
                afrag[s][n][e] = f2bf(fmaf(hik[s][e], wc[e], wa[e]));
                ccn[n] = fmaf(hik[s][e], wb[e], ccn[n]);
            }
        }
    }
    float w2v[3][4], cbv[3][4];
    #pragma unroll
    for (int n = 0; n < 3; ++n) {
        ccn[n] += __shfl_xor(ccn[n], 16, 64);
        ccn[n] += __shfl_xor(ccn[n], 32, 64);         // full k-sum, all lanes
        int c = n * 16 + l15;
        float cb = (c < A) ? (ccn[n] + b1[c]) : 0.f;
        #pragma unroll
        for (int r = 0; r < 4; ++r) {
            int a = n * 16 + l4 * 4 + r;
            cbv[n][r] = __shfl(cb, l4 * 4 + r, 16);   // zero already for a>=A
            w2v[n][r] = (a < A) ? w2[a] : 0.f;
        }
    }
    __syncthreads();                           // staging complete

    float oacc[4] = {0.f, 0.f, 0.f, 0.f};
    int mmax = (i >> 4) + 1;                   // block-uniform
    int sw = (l15 & 7) << 3;
    int m = 0;

    for (; m + 1 < mmax; m += 2) {             // 2-wide: independent A/B streams
        int rowA = m * 16 + l15, rowB = rowA + 16;
        const short* browA = tile + rowA * 64;
        const short* browB = tile + rowB * 64;
        short8 a0 = *(const short8*)(browA + ((l4 * 8) ^ sw));
        short8 a1 = *(const short8*)(browA + ((32 + l4 * 8) ^ sw));
        short8 bb0 = *(const short8*)(browB + ((l4 * 8) ^ sw));
        short8 bb1 = *(const short8*)(browB + ((32 + l4 * 8) ^ sw));
        floatx4 cA0 = {cbv[0][0], cbv[0][1], cbv[0][2], cbv[0][3]};
        floatx4 cA1 = {cbv[1][0], cbv[1][1], cbv[1][2], cbv[1][3]};
        floatx4 cA2 = {cbv[2][0], cbv[2][1], cbv[2][2], cbv[2][3]};
        floatx4 cB0 = cA0, cB1 = cA1, cB2 = cA2;
        cA0 = __builtin_amdgcn_mfma_f32_16x16x32_bf16(afrag[0][0], a0, cA0, 0, 0, 0);
        cB0 = __builtin_amdgcn_mfma_f32_16x16x32_bf16(afrag[0][0], bb0, cB0, 0, 0, 0);
        cA1 = __builtin_amdgcn_mfma_f32_16x16x32_bf16(afrag[0][1], a0, cA1, 0, 0, 0);
        cB1 = __builtin_amdgcn_mfma_f32_16x16x32_bf16(afrag[0][1], bb0, cB1, 0, 0, 0);
        cA2 = __builtin_amdgcn_mfma_f32_16x16x32_bf16(afrag[0][2], a0, cA2, 0, 0, 0);
        cB2 = __builtin_amdgcn_mfma_f32_16x16x32_bf16(afrag[0][2], bb0, cB2, 0, 0, 0);
        cA0 = __builtin_amdgcn_mfma_f32_16x16x32_bf16(afrag[1][0], a1, cA0, 0, 0, 0);
        cB0 = __builtin_amdgcn_mfma_f32_16x16x32_bf16(afrag[1][0], bb1, cB0, 0, 0, 0);
        cA1 = __builtin_amdgcn_mfma_f32_16x16x32_bf16(afrag[1][1], a1, cA1, 0, 0, 0);
        cB1 = __builtin_amdgcn_mfma_f32_16x16x32_bf16(afrag[1][1], bb1, cB1, 0, 0, 0);
        cA2 = __builtin_amdgcn_mfma_f32_16x16x32_bf16(afrag[1][2], a1, cA2, 0, 0, 0);
        cB2 = __builtin_amdgcn_mfma_f32_16x16x32_bf16(afrag[1][2], bb1, cB2, 0, 0, 0);
        float sA0 = 0.f, sA1 = 0.f, sA2 = 0.f, sB0 = 0.f, sB1 = 0.f, sB2 = 0.f;
        #pragma unroll
        for (int r = 0; r < 4; ++r) {
            sA0 = fmaf(fmaxf(cA0[r], 0.01f * cA0[r]), w2v[0][r], sA0);
            sB0 = fmaf(fmaxf(cB0[r], 0.01f * cB0[r]), w2v[0][r], sB0);
            sA1 = fmaf(fmaxf(cA1[r], 0.01f * cA1[r]), w2v[1][r], sA1);
            sB1 = fmaf(fmaxf(cB1[r], 0.01f * cB1[r]), w2v[1][r], sB1);
            sA2 = fmaf(fmaxf(cA2[r], 0.01f * cA2[r]), w2v[2][r], sA2);
            sB2 = fmaf(fmaxf(cB2[r], 0.01f * cB2[r]), w2v[2][r], sB2);
        }
        float spA = (sA0 + sA1) + sA2;
        float spB = (sB0 + sB1) + sB2;
        spA += __shfl_xor(spA, 16, 64);
        spB += __shfl_xor(spB, 16, 64);
        spA += __shfl_xor(spA, 32, 64);
        spB += __shfl_xor(spB, 32, 64);
        float scA = (rowA <= i) ? spA + b2v : 0.f;
        float scB = (rowB <= i) ? spB + b2v : 0.f;

        const float* hjA = h_b + (size_t)(m * 16) * H + lane;
        const float* hjB = hjA + 16 * H;
        #pragma unroll
        for (int rb = 0; rb < 4; ++rb) {
            #pragma unroll
            for (int q = 0; q < 4; ++q) {
                int jq = rb * 4 + q;
                float sqA = __int_as_float(
                    __builtin_amdgcn_readlane(__float_as_int(scA), jq));
                float sqB = __int_as_float(
                    __builtin_amdgcn_readlane(__float_as_int(scB), jq));
                oacc[rb] = fmaf(sqA, hjA[jq * H], oacc[rb]);
                oacc[rb] = fmaf(sqB, hjB[jq * H], oacc[rb]);
            }
        }
    }
    if (m < mmax) {                            // odd tail: single m-tile
        int row = m * 16 + l15;
        const short* brow = tile + row * 64;
        short8 a0 = *(const short8*)(brow + ((l4 * 8) ^ sw));
        short8 a1 = *(const short8*)(brow + ((32 + l4 * 8) ^ sw));
        floatx4 c0 = {cbv[0][0], cbv[0][1], cbv[0][2], cbv[0][3]};
        floatx4 c1 = {cbv[1][0], cbv[1][1], cbv[1][2], cbv[1][3]};
        floatx4 c2 = {cbv[2][0], cbv[2][1], cbv[2][2], cbv[2][3]};
        c0 = __builtin_amdgcn_mfma_f32_16x16x32_bf16(afrag[0][0], a0, c0, 0, 0, 0);
        c1 = __builtin_amdgcn_mfma_f32_16x16x32_bf16(afrag[0][1], a0, c1, 0, 0, 0);
        c2 = __builtin_amdgcn_mfma_f32_16x16x32_bf16(afrag[0][2], a0, c2, 0, 0, 0);
        c0 = __builtin_amdgcn_mfma_f32_16x16x32_bf16(afrag[1][0], a1, c0, 0, 0, 0);
        c1 = __builtin_amdgcn_mfma_f32_16x16x32_bf16(afrag[1][1], a1, c1, 0, 0, 0);
        c2 = __builtin_amdgcn_mfma_f32_16x16x32_bf16(afrag[1][2], a1, c2, 0, 0, 0);
        float s0 = 0.f, s1 = 0.f, s2 = 0.f;
        #pragma unroll
        for (int r = 0; r < 4; ++r) {
            s0 = fmaf(fmaxf(c0[r], 0.01f * c0[r]), w2v[0][r], s0);
            s1 = fmaf(fmaxf(c1[r], 0.01f * c1[r]), w2v[1][r], s1);
            s2 = fmaf(fmaxf(c2[r], 0.01f * c2[r]), w2v[2][r], s2);
        }
        float sp = (s0 + s1) + s2;
        sp += __shfl_xor(sp, 16, 64);
        sp += __shfl_xor(sp, 32, 64);
        float sc = (row <= i) ? sp + b2v : 0.f;
        const float* hjb = h_b + (size_t)(m * 16) * H + lane;
        #pragma unroll
        for (int rb = 0; rb < 4; ++rb) {
            #pragma unroll
            for (int q = 0; q < 4; ++q) {
                int jq = rb * 4 + q;
                float sq = __int_as_float(
                    __builtin_amdgcn_readlane(__float_as_int(sc), jq));
                oacc[rb] = fmaf(sq, hjb[jq * H], oacc[rb]);
            }
        }
    }

    out[((size_t)b * L + i) * H + lane] = (oacc[0] + oacc[1]) + (oacc[2] + oacc[3]);
}

extern "C" void kernel_launch(void* const* d_in, const int* in_sizes, int n_in,
                              void* d_out, int out_size, void* d_ws, size_t ws_size,
                              hipStream_t stream) {
    const float* x    = (const float*)d_in[0];
    const float* ln_w = (const float*)d_in[1];
    const float* ln_b = (const float*)d_in[2];
    const float* w1   = (const float*)d_in[3];
    const float* b1   = (const float*)d_in[4];
    const float* w2   = (const float*)d_in[5];
    const float* b2   = (const float*)d_in[6];
    float* out = (float*)d_out;

    float* h_ws   = (float*)d_ws;                             // B*L*H f32
    short* hb16_ws = (short*)(h_ws + (size_t)B * L * H);      // B*L*H bf16 (swizzled)
    float* w1a_r  = (float*)(hb16_ws + (size_t)B * L * H);    // 3072 f32
    float* w1b_r  = w1a_r + 3072;                             // 3072 f32
    float* w1c_r  = w1b_r + 3072;                             // 3072 f32

    prep_kernel<<<(B * L) / 4, 256, 0, stream>>>(x, ln_w, ln_b, w1, h_ws,
                                                 hb16_ws, w1a_r, w1b_r, w1c_r);
    score_kernel<<<B * 50, 256, 0, stream>>>(h_ws, hb16_ws, w1a_r, w1b_r, w1c_r,
                                             b1, w2, b2, out);
}

// Round 16
// 39.713 us; speedup vs baseline: 1.1936x; 1.1936x over previous
//
#include <hip/hip_runtime.h>

#define B 32
#define L 200
#define DIN 64
#define H 64
#define A 36

typedef __attribute__((ext_vector_type(8))) short short8;   // bf16 MFMA fragment
typedef __attribute__((ext_vector_type(4))) float floatx4;  // MFMA accumulator
typedef __attribute__((ext_vector_type(8))) float floatx8;

static __device__ __forceinline__ short f2bf(float f) {
    union { float f; unsigned u; } v; v.f = f;
    unsigned r = (v.u + 0x7FFF + ((v.u >> 16) & 1)) >> 16;  // RNE
    return (short)r;
}

// Kernel 1: h = x@ln_w + ln_b ; h f32, hb16 pre-swizzled bf16. cc computed in
// score prologue. Block 0 reorders w1a/w1b/w1c into fragment order.
__global__ __launch_bounds__(256) void prep_kernel(
    const float* __restrict__ x, const float* __restrict__ ln_w,
    const float* __restrict__ ln_b, const float* __restrict__ w1,
    float* __restrict__ h_out, short* __restrict__ hb16_out,
    float* __restrict__ w1a_r, float* __restrict__ w1b_r, float* __restrict__ w1c_r)
{
    int wave = threadIdx.x >> 6;
    int lane = threadIdx.x & 63;
    int bl = __builtin_amdgcn_readfirstlane(blockIdx.x * 4 + wave);
    const float* xr = x + (size_t)bl * DIN;
    float p0 = ln_b[lane], p1 = 0.f;
    #pragma unroll
    for (int d = 0; d < DIN; d += 2) {
        p0 = fmaf(xr[d],     ln_w[d * H + lane],       p0);   // xr uniform -> s_load
        p1 = fmaf(xr[d + 1], ln_w[(d + 1) * H + lane], p1);
    }
    float acc = p0 + p1;
    h_out[(size_t)bl * H + lane] = acc;
    int j = bl % L;
    hb16_out[(size_t)bl * H + (lane ^ ((j & 7) << 3))] = f2bf(acc);   // swizzled
    if (blockIdx.x == 0) {
        // fragment-order tables: idx = ((s*3+n)*64 + lane)*8 + e
        for (int idx = threadIdx.x; idx < 2 * 3 * 64 * 8; idx += 256) {
            int e = idx & 7, ln = (idx >> 3) & 63, sn = idx >> 9;
            int s = sn / 3, n = sn - 3 * s;
            int k = s * 32 + (ln >> 4) * 8 + e;
            int c = n * 16 + (ln & 15);
            bool cv = c < A;
            w1a_r[idx] = cv ? w1[k * A + c] : 0.f;
            w1b_r[idx] = cv ? w1[(H + k) * A + c] : 0.f;
            w1c_r[idx] = cv ? w1[(2 * H + k) * A + c] : 0.f;
        }
    }
}

// Kernel 2: block=(b,g), g reversed (longest first); wave w owns i = 4g+w.
// __launch_bounds__(256) (NOT default-1024: that caps VGPR at 64 and spills).
// 2-WIDE m-loop: two independent m-tile streams per iteration.
__global__ __launch_bounds__(256) void score_kernel(
    const float* __restrict__ h, const short* __restrict__ hb16,
    const float* __restrict__ w1a_r, const float* __restrict__ w1b_r,
    const float* __restrict__ w1c_r, const float* __restrict__ b1,
    const float* __restrict__ w2, const float* __restrict__ b2,
    float* __restrict__ out)
{
    int blk = blockIdx.x;
    int b  = blk / 50;
    int g  = 49 - (blk - b * 50);            // longest blocks dispatch first
    int wave = threadIdx.x >> 6;
    int lane = threadIdx.x & 63;
    int i = __builtin_amdgcn_readfirstlane(4 * g + wave);     // 0..199
    int l15 = lane & 15, l4 = lane >> 4;

    __shared__ __align__(16) short tile[208 * 64];  // pre-swizzled rows

    const short* hb16b = hb16 + (size_t)b * L * H;
    const float* h_b   = h + (size_t)b * L * H;

    // ---- stage rows 0 .. (4g+3 | 15): 2..26 chunks of 8 rows ----
    int maxrow = 4 * g + 3;
    int nch = (((maxrow | 15) + 1) + 7) >> 3;
    for (int c = wave; c < nch; c += 4) {
        int j = c * 8 + (lane >> 3); if (j > L - 1) j = L - 1;
        const short* src = hb16b + (size_t)j * H + (lane & 7) * 8;
        __builtin_amdgcn_global_load_lds(
            (const __attribute__((address_space(1))) void*)src,
            (__attribute__((address_space(3))) void*)&tile[c * 512],
            16, 0, 0);
    }

    // ---- prologue (overlaps staging flight) ----
    const float* hi = h_b + (size_t)i * H;            // uniform -> s_load
    float b2v = b2[0];
    float hik[2][8];
    #pragma unroll
    for (int s = 0; s < 2; ++s) {
        floatx8 hv = *(const floatx8*)(hi + s * 32 + l4 * 8);
        #pragma unroll
        for (int e = 0; e < 8; ++e) hik[s][e] = hv[e];
    }
    // cc[i,c] for c = n*16+l15 : 48 fma vs w1b_r, then reduce over l4 groups
    float ccn[3];
    short8 afrag[2][3];
    #pragma unroll
    for (int n = 0; n < 3; ++n) ccn[n] = 0.f;
    #pragma unroll
    for (int s = 0; s < 2; ++s) {
        #pragma unroll
        for (int n = 0; n < 3; ++n) {
            int base = (((s * 3 + n) * 64) + lane) * 8;
            floatx8 wa = *(const floatx8*)&w1a_r[base];
            floatx8 wb = *(const floatx8*)&w1b_r[base];
            floatx8 wc = *(const floatx8*)&w1c_r[base];
            #pragma unroll
            for (int e = 0; e < 8; ++e) {
                afrag[s][n][e] = f2bf(fmaf(hik[s][e], wc[e], wa[e]));
                ccn[n] = fmaf(hik[s][e], wb[e], ccn[n]);
            }
        }
    }
    float w2v[3][4], cbv[3][4];
    #pragma unroll
    for (int n = 0; n < 3; ++n) {
        ccn[n] += __shfl_xor(ccn[n], 16, 64);
        ccn[n] += __shfl_xor(ccn[n], 32, 64);         // full k-sum, all lanes
        int c = n * 16 + l15;
        float cb = (c < A) ? (ccn[n] + b1[c]) : 0.f;
        #pragma unroll
        for (int r = 0; r < 4; ++r) {
            int a = n * 16 + l4 * 4 + r;
            cbv[n][r] = __shfl(cb, l4 * 4 + r, 16);   // zero already for a>=A
            w2v[n][r] = (a < A) ? w2[a] : 0.f;
        }
    }
    __syncthreads();                           // staging complete

    float oacc[4] = {0.f, 0.f, 0.f, 0.f};
    int mmax = (i >> 4) + 1;                   // block-uniform
    int sw = (l15 & 7) << 3;
    int m = 0;

    for (; m + 1 < mmax; m += 2) {             // 2-wide: independent A/B streams
        int rowA = m * 16 + l15, rowB = rowA + 16;
        const short* browA = tile + rowA * 64;
        const short* browB = tile + rowB * 64;
        short8 a0 = *(const short8*)(browA + ((l4 * 8) ^ sw));
        short8 a1 = *(const short8*)(browA + ((32 + l4 * 8) ^ sw));
        short8 bb0 = *(const short8*)(browB + ((l4 * 8) ^ sw));
        short8 bb1 = *(const short8*)(browB + ((32 + l4 * 8) ^ sw));
        floatx4 cA0 = {cbv[0][0], cbv[0][1], cbv[0][2], cbv[0][3]};
        floatx4 cA1 = {cbv[1][0], cbv[1][1], cbv[1][2], cbv[1][3]};
        floatx4 cA2 = {cbv[2][0], cbv[2][1], cbv[2][2], cbv[2][3]};
        floatx4 cB0 = cA0, cB1 = cA1, cB2 = cA2;
        cA0 = __builtin_amdgcn_mfma_f32_16x16x32_bf16(afrag[0][0], a0, cA0, 0, 0, 0);
        cB0 = __builtin_amdgcn_mfma_f32_16x16x32_bf16(afrag[0][0], bb0, cB0, 0, 0, 0);
        cA1 = __builtin_amdgcn_mfma_f32_16x16x32_bf16(afrag[0][1], a0, cA1, 0, 0, 0);
        cB1 = __builtin_amdgcn_mfma_f32_16x16x32_bf16(afrag[0][1], bb0, cB1, 0, 0, 0);
        cA2 = __builtin_amdgcn_mfma_f32_16x16x32_bf16(afrag[0][2], a0, cA2, 0, 0, 0);
        cB2 = __builtin_amdgcn_mfma_f32_16x16x32_bf16(afrag[0][2], bb0, cB2, 0, 0, 0);
        cA0 = __builtin_amdgcn_mfma_f32_16x16x32_bf16(afrag[1][0], a1, cA0, 0, 0, 0);
        cB0 = __builtin_amdgcn_mfma_f32_16x16x32_bf16(afrag[1][0], bb1, cB0, 0, 0, 0);
        cA1 = __builtin_amdgcn_mfma_f32_16x16x32_bf16(afrag[1][1], a1, cA1, 0, 0, 0);
        cB1 = __builtin_amdgcn_mfma_f32_16x16x32_bf16(afrag[1][1], bb1, cB1, 0, 0, 0);
        cA2 = __builtin_amdgcn_mfma_f32_16x16x32_bf16(afrag[1][2], a1, cA2, 0, 0, 0);
        cB2 = __builtin_amdgcn_mfma_f32_16x16x32_bf16(afrag[1][2], bb1, cB2, 0, 0, 0);
        float sA0 = 0.f, sA1 = 0.f, sA2 = 0.f, sB0 = 0.f, sB1 = 0.f, sB2 = 0.f;
        #pragma unroll
        for (int r = 0; r < 4; ++r) {
            sA0 = fmaf(fmaxf(cA0[r], 0.01f * cA0[r]), w2v[0][r], sA0);
            sB0 = fmaf(fmaxf(cB0[r], 0.01f * cB0[r]), w2v[0][r], sB0);
            sA1 = fmaf(fmaxf(cA1[r], 0.01f * cA1[r]), w2v[1][r], sA1);
            sB1 = fmaf(fmaxf(cB1[r], 0.01f * cB1[r]), w2v[1][r], sB1);
            sA2 = fmaf(fmaxf(cA2[r], 0.01f * cA2[r]), w2v[2][r], sA2);
            sB2 = fmaf(fmaxf(cB2[r], 0.01f * cB2[r]), w2v[2][r], sB2);
        }
        float spA = (sA0 + sA1) + sA2;
        float spB = (sB0 + sB1) + sB2;
        spA += __shfl_xor(spA, 16, 64);
        spB += __shfl_xor(spB, 16, 64);
        spA += __shfl_xor(spA, 32, 64);
        spB += __shfl_xor(spB, 32, 64);
        float scA = (rowA <= i) ? spA + b2v : 0.f;
        float scB = (rowB <= i) ? spB + b2v : 0.f;

        const float* hjA = h_b + (size_t)(m * 16) * H + lane;
        const float* hjB = hjA + 16 * H;
        #pragma unroll
        for (int rb = 0; rb < 4; ++rb) {
            #pragma unroll
            for (int q = 0; q < 4; ++q) {
                int jq = rb * 4 + q;
                float sqA = __int_as_float(
                    __builtin_amdgcn_readlane(__float_as_int(scA), jq));
                float sqB = __int_as_float(
                    __builtin_amdgcn_readlane(__float_as_int(scB), jq));
                oacc[rb] = fmaf(sqA, hjA[jq * H], oacc[rb]);
                oacc[rb] = fmaf(sqB, hjB[jq * H], oacc[rb]);
            }
        }
    }
    if (m < mmax) {                            // odd tail: single m-tile
        int row = m * 16 + l15;
        const short* brow = tile + row * 64;
        short8 a0 = *(const short8*)(brow + ((l4 * 8) ^ sw));
        short8 a1 = *(const short8*)(brow + ((32 + l4 * 8) ^ sw));
        floatx4 c0 = {cbv[0][0], cbv[0][1], cbv[0][2], cbv[0][3]};
        floatx4 c1 = {cbv[1][0], cbv[1][1], cbv[1][2], cbv[1][3]};
        floatx4 c2 = {cbv[2][0], cbv[2][1], cbv[2][2], cbv[2][3]};
        c0 = __builtin_amdgcn_mfma_f32_16x16x32_bf16(afrag[0][0], a0, c0, 0, 0, 0);
        c1 = __builtin_amdgcn_mfma_f32_16x16x32_bf16(afrag[0][1], a0, c1, 0, 0, 0);
        c2 = __builtin_amdgcn_mfma_f32_16x16x32_bf16(afrag[0][2], a0, c2, 0, 0, 0);
        c0 = __builtin_amdgcn_mfma_f32_16x16x32_bf16(afrag[1][0], a1, c0, 0, 0, 0);
        c1 = __builtin_amdgcn_mfma_f32_16x16x32_bf16(afrag[1][1], a1, c1, 0, 0, 0);
        c2 = __builtin_amdgcn_mfma_f32_16x16x32_bf16(afrag[1][2], a1, c2, 0, 0, 0);
        float s0 = 0.f, s1 = 0.f, s2 = 0.f;
        #pragma unroll
        for (int r = 0; r < 4; ++r) {
            s0 = fmaf(fmaxf(c0[r], 0.01f * c0[r]), w2v[0][r], s0);
            s1 = fmaf(fmaxf(c1[r], 0.01f * c1[r]), w2v[1][r], s1);
            s2 = fmaf(fmaxf(c2[r], 0.01f * c2[r]), w2v[2][r], s2);
        }
        float sp = (s0 + s1) + s2;
        sp += __shfl_xor(sp, 16, 64);
        sp += __shfl_xor(sp, 32, 64);
        float sc = (row <= i) ? sp + b2v : 0.f;
        const float* hjb = h_b + (size_t)(m * 16) * H + lane;
        #pragma unroll
        for (int rb = 0; rb < 4; ++rb) {
            #pragma unroll
            for (int q = 0; q < 4; ++q) {
                int jq = rb * 4 + q;
                float sq = __int_as_float(
                    __builtin_amdgcn_readlane(__float_as_int(sc), jq));
                oacc[rb] = fmaf(sq, hjb[jq * H], oacc[rb]);
            }
        }
    }

    out[((size_t)b * L + i) * H + lane] = (oacc[0] + oacc[1]) + (oacc[2] + oacc[3]);
}

extern "C" void kernel_launch(void* const* d_in, const int* in_sizes, int n_in,
                              void* d_out, int out_size, void* d_ws, size_t ws_size,
                              hipStream_t stream) {
    const float* x    = (const float*)d_in[0];
    const float* ln_w = (const float*)d_in[1];
    const float* ln_b = (const float*)d_in[2];
    const float* w1   = (const float*)d_in[3];
    const float* b1   = (const float*)d_in[4];
    const float* w2   = (const float*)d_in[5];
    const float* b2   = (const float*)d_in[6];
    float* out = (float*)d_out;

    float* h_ws   = (float*)d_ws;                             // B*L*H f32
    short* hb16_ws = (short*)(h_ws + (size_t)B * L * H);      // B*L*H bf16 (swizzled)
    float* w1a_r  = (float*)(hb16_ws + (size_t)B * L * H);    // 3072 f32
    float* w1b_r  = w1a_r + 3072;                             // 3072 f32
    float* w1c_r  = w1b_r + 3072;                             // 3072 f32

    prep_kernel<<<(B * L) / 4, 256, 0, stream>>>(x, ln_w, ln_b, w1, h_ws,
                                                 hb16_ws, w1a_r, w1b_r, w1c_r);
    score_kernel<<<B * 50, 256, 0, stream>>>(h_ws, hb16_ws, w1a_r, w1b_r, w1c_r,
                                             b1, w2, b2, out);
}